// Round 7
// baseline (1915.129 us; speedup 1.0000x reference)
//
#include <hip/hip_runtime.h>
#include <math.h>

#define SS   96            // S
#define TM   96            // TM1
#define BB   8             // B
#define VV   32000         // V
#define EE   256           // E
#define HH   512           // H
#define NTOK (SS + TM)     // 192
#define G4   (4 * HH)      // 2048
#define NEGF (-1e30f)
#define LBLK 16            // k_lstm blocks (64 waves total)

typedef __attribute__((ext_vector_type(8))) short short8;
typedef __attribute__((ext_vector_type(4))) float f32x4;
typedef unsigned long long u64;

// ---- workspace layout (float offsets) ----
#define XIH_OFF   ((size_t)0)
#define XIH_SZ    ((size_t)NTOK * BB * G4)       // 3,145,728 f
#define HALL_OFF  (XIH_OFF + XIH_SZ)
#define HALL_SZ   ((size_t)NTOK * BB * HH)       // 786,432 f
#define Q_OFF     (HALL_OFF + HALL_SZ)
#define Q_SZ      ((size_t)TM * BB * HH)         // 393,216 f
#define PPTR_OFF  (Q_OFF + Q_SZ)
#define ASENT_OFF (PPTR_OFF + (size_t)(TM * BB))
#define SSUM_OFF  (ASENT_OFF + (size_t)(TM * BB))
#define LSTAR_OFF (SSUM_OFF + (size_t)(TM * BB))
#define FLAG_OFF  (LSTAR_OFF + (size_t)(TM * BB))   // 64 wave flags x 16 u32 (64B spacing)
#define WHHBF_OFF (FLAG_OFF + (size_t)1024)
#define WHHBF_SZF ((size_t)G4 * HH / 2)             // 524,288 f (2048x512 bf16)
#define HBF_OFF   (WHHBF_OFF + WHHBF_SZF)
#define HBF_SZF   ((size_t)2 * BB * HH / 2)         // 4,096 f (2 x 8 x 512 bf16, dbuf)
#define ABF_OFF   (HBF_OFF + HBF_SZF)
#define ABF_SZF   ((size_t)(768 * HH) / 2)          // 196,608 f
#define WBF_OFF   (ABF_OFF + ABF_SZF)
#define WBF_SZF   ((size_t)VV * HH / 2)             // 8,192,000 f
#define NEED_F    (WBF_OFF + WBF_SZF)

__device__ __forceinline__ float sigf(float x) { return 1.f / (1.f + __expf(-x)); }

__device__ __forceinline__ unsigned short f2bf(float x) {
    unsigned bits = __float_as_uint(x);
    bits += 0x7FFFu + ((bits >> 16) & 1u);   // RNE
    return (unsigned short)(bits >> 16);
}

// ============ Kernel 1: Xih[tok][row] = emb_eff[idx[tok]] . W_ih[row] + bias ============
__global__ void __launch_bounds__(256) k_xih(const int* __restrict__ src,
                                             const int* __restrict__ tgt,
                                             const float* __restrict__ emb,
                                             const float* __restrict__ Wih,
                                             const float* __restrict__ bih,
                                             const float* __restrict__ bhh,
                                             float* __restrict__ xih) {
    __shared__ float xs[16][EE];   // 16 KB
    const int tok0 = blockIdx.x * 16;
    const int row0 = blockIdx.y * 256;
    const int tid  = threadIdx.x;

    for (int e = tid; e < 16 * EE; e += 256) {
        int tk = e >> 8;          // EE == 256
        int k  = e & 255;
        int tau = tok0 + tk;
        int idx = (tau < SS * BB) ? src[tau] : tgt[tau - SS * BB];
        xs[tk][k] = (idx == 0) ? 0.f : emb[(size_t)idx * EE + k];   // PAD row zeroed
    }
    __syncthreads();

    const int row = row0 + tid;
    const float bias = bih[row] + bhh[row];
    float acc[16];
#pragma unroll
    for (int r = 0; r < 16; ++r) acc[r] = bias;

    const float4* w4 = (const float4*)(Wih + (size_t)row * EE);
    for (int k4 = 0; k4 < EE / 4; ++k4) {
        float4 w = w4[k4];
#pragma unroll
        for (int r = 0; r < 16; ++r) {
            float4 x = *((const float4*)&xs[r][k4 * 4]);
            acc[r] += w.x * x.x + w.y * x.y + w.z * x.z + w.w * x.w;
        }
    }
#pragma unroll
    for (int r = 0; r < 16; ++r)
        xih[(size_t)(tok0 + r) * G4 + row] = acc[r];
}

// ============ generic f32 -> bf16 converter (8 elems/thread) ============
__global__ void __launch_bounds__(256) k_cvt2(const float* __restrict__ src,
                                              unsigned short* __restrict__ dst,
                                              long n) {
    size_t base = ((size_t)blockIdx.x * 256 + threadIdx.x) * 8;
    if ((long)base >= n) return;
    float4 f0 = *(const float4*)(src + base);
    float4 f1 = *(const float4*)(src + base + 4);
    uint4 o;
    o.x = (unsigned)f2bf(f0.x) | ((unsigned)f2bf(f0.y) << 16);
    o.y = (unsigned)f2bf(f0.z) | ((unsigned)f2bf(f0.w) << 16);
    o.z = (unsigned)f2bf(f1.x) | ((unsigned)f2bf(f1.y) << 16);
    o.w = (unsigned)f2bf(f1.z) | ((unsigned)f2bf(f1.w) << 16);
    *(uint4*)(dst + base) = o;
}

// ============ Kernel 2: LSTM scan via MFMA — batched coherent exchange ============
// 16 blocks x 256 thr (64 waves). Wave wv: gate-rows I0 = blk*32+wv*8 (x4 gates).
// MFMA mapping identical to rounds 4/6 (verified): col = batch, A row16 = j:
// tile0 = i/f gates, tile1 = g/o gates.
// A-fragments STREAMED from L2 each step (issued before the poll -> latency hidden).
// All cross-block traffic: raw asm, sc0 sc1 (device-coherent at L3), batched with
// a SINGLE vmcnt(0) per phase -- no per-op atomic serialization, no __syncthreads.
// h double-buffered by t-parity; per-wave monotone generation flags.
__global__ void __launch_bounds__(256, 1) k_lstm(const float* __restrict__ xih,
                                                 const unsigned short* __restrict__ whhbf,
                                                 float* __restrict__ hall,
                                                 unsigned short* __restrict__ hbf,
                                                 unsigned* __restrict__ flags) {
    const int tid = threadIdx.x;
    const int wv  = tid >> 6;
    const int l   = tid & 63;
    const int b16 = l & 15;          // MFMA col = batch (cols 8..15 = don't-care)
    const int kg  = l >> 4;          // 0..3
    const int bb  = b16 & 7;         // clamped batch (pad cols compute duplicates)
    const int I0  = blockIdx.x * 32 + wv * 8;
    unsigned* myflag = flags + (size_t)(blockIdx.x * 4 + wv) * 16;
    const unsigned* pollp = flags + (size_t)l * 16;

    // A-fragment base addrs: row16 = j = l&15: tile0 gate = j>>3 (i/f),
    // tile1 gate = 2+(j>>3) (g/o); i = I0+(j&7)
    const int j = b16;
    const unsigned short* a0p = whhbf + ((size_t)((j >> 3) * HH + I0 + (j & 7))) * HH + kg * 8;
    const unsigned short* a1p = whhbf + ((size_t)((2 + (j >> 3)) * HH + I0 + (j & 7))) * HH + kg * 8;

    // xih C-init addressing: lane (kg, reg r): row16 = 4*kg+r
    const int xgate0 = (kg >> 1);        // 0:i 1:f
    const int xgate1 = 2 + (kg >> 1);    // 2:g 3:o
    const int xi     = I0 + (kg & 1) * 4;

    float c0[4] = {0.f, 0.f, 0.f, 0.f};

    for (int t = 0; t < NTOK; ++t) {
        // ---- phase A: issue xih + A-fragment loads (plain/cached), NO wait ----
        float4 x0, x1;
        {
            const float* xb = xih + ((size_t)t * BB + bb) * G4;
            asm volatile("global_load_dwordx4 %0, %1, off"
                         : "=v"(x0) : "v"(xb + xgate0 * HH + xi));
            asm volatile("global_load_dwordx4 %0, %1, off"
                         : "=v"(x1) : "v"(xb + xgate1 * HH + xi));
        }
        short8 A0[16], A1[16];
#pragma unroll
        for (int ks = 0; ks < 16; ++ks) {
            asm volatile("global_load_dwordx4 %0, %1, off"
                         : "=v"(A0[ks]) : "v"(a0p + ks * 32));
            asm volatile("global_load_dwordx4 %0, %1, off"
                         : "=v"(A1[ks]) : "v"(a1p + ks * 32));
        }

        short8 Bf[16];
        if (t > 0) {
            // ---- phase B: poll all 64 wave flags (lane l <-> flag l), coherent ----
            unsigned v;
            do {
                asm volatile("global_load_dword %0, %1, off sc0 sc1\n\ts_waitcnt vmcnt(0)"
                             : "=v"(v) : "v"(pollp) : "memory");
            } while (v < (unsigned)t);

            // ---- phase C: batched B-fragment loads (one wait for all 16) ----
            const unsigned short* hsrc =
                hbf + ((t - 1) & 1) * (BB * HH) + (size_t)bb * HH + kg * 8;
#pragma unroll
            for (int ks = 0; ks < 16; ++ks)
                asm volatile("global_load_dwordx4 %0, %1, off sc0 sc1"
                             : "=v"(Bf[ks]) : "v"(hsrc + ks * 32) : "memory");
        }
        asm volatile("s_waitcnt vmcnt(0)" ::: "memory");
        __builtin_amdgcn_sched_barrier(0);

        f32x4 acc0 = {x0.x, x0.y, x0.z, x0.w};
        f32x4 acc1 = {x1.x, x1.y, x1.z, x1.w};
        if (t > 0) {
#pragma unroll
            for (int ks = 0; ks < 16; ++ks) {
                acc0 = __builtin_amdgcn_mfma_f32_16x16x32_bf16(A0[ks], Bf[ks], acc0, 0, 0, 0);
                acc1 = __builtin_amdgcn_mfma_f32_16x16x32_bf16(A1[ks], Bf[ks], acc1, 0, 0, 0);
            }
        }

        // activations: lanes l<32 hold i (acc0) / g (acc1); f/o at lane+32
        float hreg[4];
#pragma unroll
        for (int r = 0; r < 4; ++r) {
            float gf = __shfl_down(acc0[r], 32, 64);
            float go = __shfl_down(acc1[r], 32, 64);
            float is = sigf(acc0[r]);
            float fs = sigf(gf);
            float gv = tanhf(acc1[r]);
            float os = sigf(go);
            c0[r] = fs * c0[r] + is * gv;
            hreg[r] = os * tanhf(c0[r]);
        }

        if (l < 32 && b16 < BB) {
            const int ib = I0 + kg * 4;   // kg in {0,1}
            // f32 h for downstream kernels (plain cached; flushed at kernel end)
            *(float4*)(hall + ((size_t)t * BB + b16) * HH + ib) =
                make_float4(hreg[0], hreg[1], hreg[2], hreg[3]);
            // bf16 h publish: device-coherent store (reaches L3)
            u64 pk = (u64)f2bf(hreg[0]) | ((u64)f2bf(hreg[1]) << 16) |
                     ((u64)f2bf(hreg[2]) << 32) | ((u64)f2bf(hreg[3]) << 48);
            unsigned short* hdst = hbf + (t & 1) * (BB * HH) + (size_t)b16 * HH + ib;
            asm volatile("global_store_dwordx2 %0, %1, off sc0 sc1"
                         :: "v"(hdst), "v"(pk) : "memory");
        }

        if (t < NTOK - 1) {
            // release: drain h publishes (single wait), then raise this wave's flag
            asm volatile("s_waitcnt vmcnt(0)" ::: "memory");
            if (l == 0) {
                unsigned fv = (unsigned)(t + 1);
                asm volatile("global_store_dword %0, %1, off sc0 sc1"
                             :: "v"(myflag), "v"(fv) : "memory");
            }
        }
    }
}

// ============ Kernel 3: Q = tanh(Hdec @ W_att^T). grid TM, block 256 ============
__global__ void __launch_bounds__(256) k_q(const float* __restrict__ hall,
                                           const float* __restrict__ Watt,
                                           float* __restrict__ q) {
    __shared__ float hb[8 * 516];
    const int t = blockIdx.x, tid = threadIdx.x;
    const float* hdec = hall + (size_t)(SS + t) * (BB * HH);
    for (int e = tid; e < BB * HH; e += 256)
        hb[(e >> 9) * 516 + (e & 511)] = hdec[e];
    __syncthreads();

    for (int oi = tid; oi < BB * HH; oi += 256) {
        int b = oi & 7, ii = oi >> 3;
        const float4* w4 = (const float4*)(Watt + (size_t)ii * HH);
        const float4* h4 = (const float4*)(hb + b * 516);
        float acc = 0.f;
        for (int k4 = 0; k4 < HH / 4; ++k4) {
            float4 w = w4[k4], h = h4[k4];
            acc += w.x * h.x + w.y * h.y + w.z * h.z + w.w * h.w;
        }
        q[(size_t)(t * BB + b) * HH + ii] = tanhf(acc);
    }
}

// ============ Kernel 4: attention scores + softmax + pointer gather ============
__global__ void __launch_bounds__(256) k_att(const float* __restrict__ hall,
                                             const float* __restrict__ q,
                                             const float* __restrict__ sent,
                                             const int* __restrict__ src,
                                             const int* __restrict__ tgt,
                                             float* __restrict__ pptr,
                                             float* __restrict__ asent) {
    __shared__ float qs[HH];
    __shared__ float av[256];
    __shared__ float red[256];
    const int t = blockIdx.x, b = blockIdx.y, tid = threadIdx.x;

    for (int e = tid; e < HH; e += 256) qs[e] = q[(size_t)(t * BB + b) * HH + e];
    __syncthreads();

    const int j = tid;
    float acc = NEGF;
    if (j < SS + TM + 1) {
        bool valid = (j < SS + t + 1) || (j == SS + TM);
        if (valid) {
            const float* vptr = (j < SS + TM) ? (hall + (size_t)(j * BB + b) * HH) : sent;
            const float4* v4 = (const float4*)vptr;
            const float4* q4 = (const float4*)qs;
            float a = 0.f;
            for (int k4 = 0; k4 < HH / 4; ++k4) {
                float4 v = v4[k4], qq = q4[k4];
                a += v.x * qq.x + v.y * qq.y + v.z * qq.z + v.w * qq.w;
            }
            acc = a;
        }
    }
    red[tid] = acc;
    __syncthreads();
    for (int s2 = 128; s2 > 0; s2 >>= 1) {
        if (tid < s2) red[tid] = fmaxf(red[tid], red[tid + s2]);
        __syncthreads();
    }
    float m = red[0];
    __syncthreads();
    float e = __expf(acc - m);
    red[tid] = e;
    __syncthreads();
    for (int s2 = 128; s2 > 0; s2 >>= 1) {
        if (tid < s2) red[tid] += red[tid + s2];
        __syncthreads();
    }
    float denom = red[0];
    __syncthreads();
    float a = e / denom;
    av[tid] = a;
    __syncthreads();

    const int vs = tgt[(t + 1) * BB + b];
    float contrib = 0.f;
    if (j < SS) {
        if (src[j * BB + b] == vs) contrib += av[j];        // a_src
        if (tgt[j * BB + b] == vs) contrib += av[SS + j];   // a_tgt
    }
    red[tid] = contrib;
    __syncthreads();
    for (int s2 = 128; s2 > 0; s2 >>= 1) {
        if (tid < s2) red[tid] += red[tid + s2];
        __syncthreads();
    }
    if (tid == 0) {
        pptr[t * BB + b]  = red[0];
        asent[t * BB + b] = av[SS + TM];
    }
}

// ============ Kernel 5: vocab softmax stats via bf16 MFMA ============
__global__ void __launch_bounds__(256) k_vocab_mfma(const unsigned short* __restrict__ Abf,
                                                    const unsigned short* __restrict__ Wbf,
                                                    const int* __restrict__ tgt,
                                                    float* __restrict__ ssum,
                                                    float* __restrict__ lstar) {
    const int tid  = threadIdx.x;
    const int wave = tid >> 6;
    const int lane = tid & 63;
    const int r16  = lane & 15;
    const int kg   = lane >> 4;          // 0..3
    const int n0   = blockIdx.x * 64;

    const unsigned short* b0 = Wbf + (size_t)(n0 +  0 + r16) * HH + kg * 8;
    const unsigned short* b1 = Wbf + (size_t)(n0 + 16 + r16) * HH + kg * 8;
    const unsigned short* b2 = Wbf + (size_t)(n0 + 32 + r16) * HH + kg * 8;
    const unsigned short* b3 = Wbf + (size_t)(n0 + 48 + r16) * HH + kg * 8;

    for (int pass = 0; pass < 12; ++pass) {
        const int row0 = pass * 64 + wave * 16;
        const unsigned short* arow = Abf + (size_t)(row0 + r16) * HH + kg * 8;

        f32x4 acc0 = {0.f,0.f,0.f,0.f}, acc1 = acc0, acc2 = acc0, acc3 = acc0;
#pragma unroll
        for (int ks = 0; ks < 16; ++ks) {
            short8 a = *(const short8*)(arow + ks * 32);
            acc0 = __builtin_amdgcn_mfma_f32_16x16x32_bf16(a, *(const short8*)(b0 + ks * 32), acc0, 0, 0, 0);
            acc1 = __builtin_amdgcn_mfma_f32_16x16x32_bf16(a, *(const short8*)(b1 + ks * 32), acc1, 0, 0, 0);
            acc2 = __builtin_amdgcn_mfma_f32_16x16x32_bf16(a, *(const short8*)(b2 + ks * 32), acc2, 0, 0, 0);
            acc3 = __builtin_amdgcn_mfma_f32_16x16x32_bf16(a, *(const short8*)(b3 + ks * 32), acc3, 0, 0, 0);
        }

#pragma unroll
        for (int reg = 0; reg < 4; ++reg) {
            const int rowg = row0 + 4 * kg + reg;
            const int vs = tgt[BB + rowg];
            int cg;
            cg = n0 +  0 + r16; if (cg == vs) lstar[rowg] = acc0[reg];
            cg = n0 + 16 + r16; if (cg == vs) lstar[rowg] = acc1[reg];
            cg = n0 + 32 + r16; if (cg == vs) lstar[rowg] = acc2[reg];
            cg = n0 + 48 + r16; if (cg == vs) lstar[rowg] = acc3[reg];

            float v = __expf(acc0[reg]) + __expf(acc1[reg]) +
                      __expf(acc2[reg]) + __expf(acc3[reg]);
            v += __shfl_xor(v, 1, 64);
            v += __shfl_xor(v, 2, 64);
            v += __shfl_xor(v, 4, 64);
            v += __shfl_xor(v, 8, 64);
            if (r16 == 0) atomicAdd(&ssum[rowg], v);
        }
    }
}

// ============ Kernel 5-fallback: f32 vocab stats (used if ws too small) ============
__global__ void __launch_bounds__(256) k_vocab_f32(const float* __restrict__ hall,
                                                   const float* __restrict__ Wread,
                                                   const int* __restrict__ tgt,
                                                   float* __restrict__ ssum,
                                                   float* __restrict__ lstar) {
    __shared__ float hs[32 * HH];   // 64 KB
    const int tid = threadIdx.x;
    const int v0 = blockIdx.x * 512 + tid * 2;
    const int v1 = v0 + 1;
    const bool g0 = v0 < VV, g1 = v1 < VV;
    const float4* w40 = (const float4*)(Wread + (size_t)(g0 ? v0 : 0) * HH);
    const float4* w41 = (const float4*)(Wread + (size_t)(g1 ? v1 : 0) * HH);
    const int rbase0 = blockIdx.y * 128;

    for (int ch = 0; ch < 4; ++ch) {
        const int rbase = rbase0 + ch * 32;
        const float4* sp4 = (const float4*)(hall + ((size_t)SS * BB + rbase) * HH);
        float4* hs4 = (float4*)hs;
        for (int e = tid; e < 32 * HH / 4; e += 256) hs4[e] = sp4[e];
        __syncthreads();

        float acc0[32], acc1[32];
#pragma unroll
        for (int r = 0; r < 32; ++r) { acc0[r] = 0.f; acc1[r] = 0.f; }

        for (int k4 = 0; k4 < HH / 4; ++k4) {
            float4 w0 = w40[k4];
            float4 w1 = w41[k4];
#pragma unroll
            for (int r = 0; r < 32; ++r) {
                float4 h = *((const float4*)(hs + r * HH + k4 * 4));
                acc0[r] += w0.x * h.x + w0.y * h.y + w0.z * h.z + w0.w * h.w;
                acc1[r] += w1.x * h.x + w1.y * h.y + w1.z * h.z + w1.w * h.w;
            }
        }

#pragma unroll
        for (int r = 0; r < 32; ++r) {
            const int row = rbase + r;
            float val = 0.f;
            if (g0) val += __expf(acc0[r]);
            if (g1) val += __expf(acc1[r]);
#pragma unroll
            for (int d = 32; d > 0; d >>= 1) val += __shfl_xor(val, d, 64);
            if ((tid & 63) == 0) atomicAdd(&ssum[row], val);
            const int vs = tgt[row + BB];
            if (g0 && v0 == vs) lstar[row] = acc0[r];
            else if (g1 && v1 == vs) lstar[row] = acc1[r];
        }
        __syncthreads();
    }
}

// ============ Kernel 6: gold log-likelihoods + per-batch sums ============
__global__ void __launch_bounds__(768) k_final(const float* __restrict__ pptr,
                                               const float* __restrict__ asent,
                                               const float* __restrict__ ssum,
                                               const float* __restrict__ lstar,
                                               const int* __restrict__ tgt,
                                               float* __restrict__ out) {
    __shared__ float g[TM * BB], gp[TM * BB];
    const int tid = threadIdx.x;          // = t*8+b
    const int vs = tgt[tid + BB];
    const float pv = __expf(lstar[tid]) / ssum[tid];
    const float ps = pptr[tid];
    const float as = asent[tid];
    if (vs != 0) {
        g[tid]  = logf(ps + pv * as);
        gp[tid] = logf(ps + as);
    } else {
        g[tid] = 0.f; gp[tid] = 0.f;
    }
    __syncthreads();
    if (tid < BB) {
        float s1 = 0.f, s2 = 0.f;
        for (int t = 0; t < TM; ++t) { s1 += g[t * BB + tid]; s2 += gp[t * BB + tid]; }
        out[tid] = s1;
        out[BB + tid] = s2;
    }
}

extern "C" void kernel_launch(void* const* d_in, const int* in_sizes, int n_in,
                              void* d_out, int out_size, void* d_ws, size_t ws_size,
                              hipStream_t stream) {
    (void)in_sizes; (void)n_in; (void)out_size;
    const int*   src   = (const int*)d_in[0];
    const int*   tgt   = (const int*)d_in[1];
    const float* emb   = (const float*)d_in[2];
    const float* Wih   = (const float*)d_in[3];
    const float* Whh   = (const float*)d_in[4];
    const float* bih   = (const float*)d_in[5];
    const float* bhh   = (const float*)d_in[6];
    const float* Watt  = (const float*)d_in[7];
    const float* sent  = (const float*)d_in[8];
    const float* Wread = (const float*)d_in[9];
    float* ws  = (float*)d_ws;
    float* out = (float*)d_out;

    const bool use_mfma_vocab = ws_size >= NEED_F * sizeof(float);

    // zero SSUM + LSTAR + FLAGS (contiguous)
    hipMemsetAsync((void*)(ws + SSUM_OFF), 0,
                   (size_t)(TM * BB * 2 + 1024) * sizeof(float), stream);

    k_xih<<<dim3(NTOK * BB / 16, G4 / 256), 256, 0, stream>>>(
        src, tgt, emb, Wih, bih, bhh, ws + XIH_OFF);

    // Whh -> bf16 (needed by k_lstm)
    k_cvt2<<<dim3((unsigned)((size_t)G4 * HH / 8 / 256)), 256, 0, stream>>>(
        Whh, (unsigned short*)(ws + WHHBF_OFF), (long)G4 * HH);

    {
        const float* xih = ws + XIH_OFF;
        const unsigned short* whhbf = (const unsigned short*)(ws + WHHBF_OFF);
        float* hall = ws + HALL_OFF;
        unsigned short* hbf = (unsigned short*)(ws + HBF_OFF);
        unsigned* flags = (unsigned*)(ws + FLAG_OFF);
        void* args[] = { (void*)&xih, (void*)&whhbf, (void*)&hall, (void*)&hbf, (void*)&flags };
        hipLaunchCooperativeKernel((void*)k_lstm, dim3(LBLK), dim3(256), args, 0, stream);
    }

    k_q<<<dim3(TM), 256, 0, stream>>>(ws + HALL_OFF, Watt, ws + Q_OFF);

    k_att<<<dim3(TM, BB), 256, 0, stream>>>(ws + HALL_OFF, ws + Q_OFF, sent,
                                            src, tgt, ws + PPTR_OFF, ws + ASENT_OFF);

    if (use_mfma_vocab) {
        k_cvt2<<<dim3((unsigned)((size_t)VV * HH / 8 / 256)), 256, 0, stream>>>(
            Wread, (unsigned short*)(ws + WBF_OFF), (long)VV * HH);
        k_cvt2<<<dim3((unsigned)((size_t)768 * HH / 8 / 256)), 256, 0, stream>>>(
            ws + HALL_OFF + (size_t)SS * BB * HH, (unsigned short*)(ws + ABF_OFF),
            (long)768 * HH);
        k_vocab_mfma<<<dim3(VV / 64), 256, 0, stream>>>(
            (const unsigned short*)(ws + ABF_OFF),
            (const unsigned short*)(ws + WBF_OFF),
            tgt, ws + SSUM_OFF, ws + LSTAR_OFF);
    } else {
        k_vocab_f32<<<dim3(63, 6), 256, 0, stream>>>(ws + HALL_OFF, Wread, tgt,
                                                     ws + SSUM_OFF, ws + LSTAR_OFF);
    }

    k_final<<<dim3(1), dim3(TM * BB), 0, stream>>>(ws + PPTR_OFF, ws + ASENT_OFF,
                                                   ws + SSUM_OFF, ws + LSTAR_OFF,
                                                   tgt, out);
}

// Round 9
// 1678.194 us; speedup vs baseline: 1.1412x; 1.1412x over previous
//
#include <hip/hip_runtime.h>
#include <math.h>

#define SS   96            // S
#define TM   96            // TM1
#define BB   8             // B
#define VV   32000         // V
#define EE   256           // E
#define HH   512           // H
#define NTOK (SS + TM)     // 192
#define G4   (4 * HH)      // 2048
#define NEGF (-1e30f)
#define LBLK 16            // k_lstm blocks (64 waves total)
#define SENTP 0xFFC1FFC1u  // bf16 NaN pair -- h (sigmoid*tanh) can never be NaN

typedef __attribute__((ext_vector_type(8))) short short8;
typedef __attribute__((ext_vector_type(4))) float f32x4;
typedef __attribute__((ext_vector_type(4))) unsigned uint32x4;   // asm-safe 16B tuple
typedef unsigned long long u64;

// ---- workspace layout (float offsets) ----
#define XIH_OFF   ((size_t)0)
#define XIH_SZ    ((size_t)NTOK * BB * G4)       // 3,145,728 f
#define HALL_OFF  (XIH_OFF + XIH_SZ)
#define HALL_SZ   ((size_t)NTOK * BB * HH)       // 786,432 f
#define Q_OFF     (HALL_OFF + HALL_SZ)
#define Q_SZ      ((size_t)TM * BB * HH)         // 393,216 f
#define PPTR_OFF  (Q_OFF + Q_SZ)
#define ASENT_OFF (PPTR_OFF + (size_t)(TM * BB))
#define SSUM_OFF  (ASENT_OFF + (size_t)(TM * BB))
#define LSTAR_OFF (SSUM_OFF + (size_t)(TM * BB))
#define HCP_OFF   (LSTAR_OFF + (size_t)(TM * BB))   // h copies: [2][16][8][512] bf16
#define HCP_SZF   ((size_t)2 * LBLK * BB * HH / 2)  // 65,536 f (256 KB)
#define WHHBF_OFF (HCP_OFF + HCP_SZF)
#define WHHBF_SZF ((size_t)G4 * HH / 2)             // 524,288 f (2048x512 bf16)
#define ABF_OFF   (WHHBF_OFF + WHHBF_SZF)
#define ABF_SZF   ((size_t)(768 * HH) / 2)          // 196,608 f
#define WBF_OFF   (ABF_OFF + ABF_SZF)
#define WBF_SZF   ((size_t)VV * HH / 2)             // 8,192,000 f
#define NEED_F    (WBF_OFF + WBF_SZF)

__device__ __forceinline__ float sigf(float x) { return 1.f / (1.f + __expf(-x)); }

__device__ __forceinline__ unsigned short f2bf(float x) {
    unsigned bits = __float_as_uint(x);
    bits += 0x7FFFu + ((bits >> 16) & 1u);   // RNE
    return (unsigned short)(bits >> 16);
}

// ============ Kernel 1: Xih[tok][row] = emb_eff[idx[tok]] . W_ih[row] + bias ============
__global__ void __launch_bounds__(256) k_xih(const int* __restrict__ src,
                                             const int* __restrict__ tgt,
                                             const float* __restrict__ emb,
                                             const float* __restrict__ Wih,
                                             const float* __restrict__ bih,
                                             const float* __restrict__ bhh,
                                             float* __restrict__ xih) {
    __shared__ float xs[16][EE];   // 16 KB
    const int tok0 = blockIdx.x * 16;
    const int row0 = blockIdx.y * 256;
    const int tid  = threadIdx.x;

    for (int e = tid; e < 16 * EE; e += 256) {
        int tk = e >> 8;          // EE == 256
        int k  = e & 255;
        int tau = tok0 + tk;
        int idx = (tau < SS * BB) ? src[tau] : tgt[tau - SS * BB];
        xs[tk][k] = (idx == 0) ? 0.f : emb[(size_t)idx * EE + k];   // PAD row zeroed
    }
    __syncthreads();

    const int row = row0 + tid;
    const float bias = bih[row] + bhh[row];
    float acc[16];
#pragma unroll
    for (int r = 0; r < 16; ++r) acc[r] = bias;

    const float4* w4 = (const float4*)(Wih + (size_t)row * EE);
    for (int k4 = 0; k4 < EE / 4; ++k4) {
        float4 w = w4[k4];
#pragma unroll
        for (int r = 0; r < 16; ++r) {
            float4 x = *((const float4*)&xs[r][k4 * 4]);
            acc[r] += w.x * x.x + w.y * x.y + w.z * x.z + w.w * x.w;
        }
    }
#pragma unroll
    for (int r = 0; r < 16; ++r)
        xih[(size_t)(tok0 + r) * G4 + row] = acc[r];
}

// ============ generic f32 -> bf16 converter (8 elems/thread) ============
__global__ void __launch_bounds__(256) k_cvt2(const float* __restrict__ src,
                                              unsigned short* __restrict__ dst,
                                              long n) {
    size_t base = ((size_t)blockIdx.x * 256 + threadIdx.x) * 8;
    if ((long)base >= n) return;
    float4 f0 = *(const float4*)(src + base);
    float4 f1 = *(const float4*)(src + base + 4);
    uint4 o;
    o.x = (unsigned)f2bf(f0.x) | ((unsigned)f2bf(f0.y) << 16);
    o.y = (unsigned)f2bf(f0.z) | ((unsigned)f2bf(f0.w) << 16);
    o.z = (unsigned)f2bf(f1.x) | ((unsigned)f2bf(f1.y) << 16);
    o.w = (unsigned)f2bf(f1.z) | ((unsigned)f2bf(f1.w) << 16);
    *(uint4*)(dst + base) = o;
}

// ============ Kernel 1b: sentinel-init the h-copy region (every launch) ============
__global__ void __launch_bounds__(256) k_sent(unsigned* __restrict__ hcp) {
    const size_t i = ((size_t)blockIdx.x * 256 + threadIdx.x) * 4;   // uint4 index
    if (i >= (size_t)2 * LBLK * BB * HH / 2) return;                 // in uints
    uint4 s = {SENTP, SENTP, SENTP, SENTP};
    *(uint4*)(hcp + i) = s;
}

// ============ Kernel 2: LSTM scan — LDS weights, sentinel-data sync (2 hops) ============
// 16 blocks x 256 thr (64 waves). Wave wv: gate-rows I0 = blk*32+wv*8 (x4 gates).
// MFMA mapping identical to rounds 4/6/7 (verified): col = batch, A row16 = j:
// tile0 = i/f gates, tile1 = g/o gates.
// Whh bf16 staged ONCE into LDS in fragment layout (128 KB/block) -> per-step A =
// 32 ds_read_b128, no global Whh traffic, no VGPR-array spill.
// h exchange: per-block private copies hcp[parity][block][b][k]; producers write all
// 16 copies (sc0 sc1 write-through, device-coherent); consumers poll THEIR copy --
// the poll load IS the B-fragment load; readiness = no 0xFFC1FFC1 sentinel dword.
// Reset-by-consumer: after intra-block syncthreads, each wave re-sentinels its
// quarter of the consumed parity copy; single vmcnt(0) drains reset+publish, which
// orders reset-complete before this block's publish becomes observable. No flags,
// no grid barrier, placement-independent.
__global__ void __launch_bounds__(256, 1) k_lstm(const float* __restrict__ xih,
                                                 const unsigned short* __restrict__ whhbf,
                                                 float* __restrict__ hall,
                                                 unsigned short* __restrict__ hcp) {
    extern __shared__ short lA[];   // 131072 B
    const int tid = threadIdx.x;
    const int wv  = tid >> 6;
    const int l   = tid & 63;
    const int b16 = l & 15;          // MFMA col = batch (cols 8..15 = don't-care)
    const int kg  = l >> 4;          // 0..3
    const int bb  = b16 & 7;         // clamped batch (pad cols compute duplicates)
    const int bx  = blockIdx.x;
    const int I0  = bx * 32 + wv * 8;

    // ---- stage A fragments into LDS (once). Slot (wv,tile,ks): 1 KB, lane-linear ----
    const int j = b16;
    const unsigned short* a0p = whhbf + ((size_t)((j >> 3) * HH + I0 + (j & 7))) * HH + kg * 8;
    const unsigned short* a1p = whhbf + ((size_t)((2 + (j >> 3)) * HH + I0 + (j & 7))) * HH + kg * 8;
    short* lA0 = lA + (((size_t)wv * 2 + 0) * 16 * 64 + l) * 8;
    short* lA1 = lA + (((size_t)wv * 2 + 1) * 16 * 64 + l) * 8;
#pragma unroll
    for (int ks = 0; ks < 16; ++ks) {
        *(short8*)(lA0 + ks * 512) = *(const short8*)(a0p + ks * 32);
        *(short8*)(lA1 + ks * 512) = *(const short8*)(a1p + ks * 32);
    }
    __syncthreads();

    // xih C-init addressing: lane (kg, reg r): row16 = 4*kg+r
    const int xgate0 = (kg >> 1);        // 0:i 1:f
    const int xgate1 = 2 + (kg >> 1);    // 2:g 3:o
    const int xi     = I0 + (kg & 1) * 4;

    float c0[4] = {0.f, 0.f, 0.f, 0.f};

    union fragu { uint32x4 u; short8 s; };

    for (int t = 0; t < NTOK; ++t) {
        // xih loads (plain cached, HBM) -- issued first, drained by the poll's waits
        const float* xb = xih + ((size_t)t * BB + bb) * G4;
        float4 x0 = *(const float4*)(xb + xgate0 * HH + xi);
        float4 x1 = *(const float4*)(xb + xgate1 * HH + xi);
        f32x4 acc0 = {x0.x, x0.y, x0.z, x0.w};
        f32x4 acc1 = {x1.x, x1.y, x1.z, x1.w};

        fragu Bf[16];
        if (t > 0) {
            // ---- poll own copy: load == B-fragment load; ready = no sentinel ----
            const unsigned short* hsrc =
                hcp + (((size_t)((t - 1) & 1) * LBLK + bx) * (BB * HH)) + (size_t)bb * HH + kg * 8;
            while (true) {
#pragma unroll
                for (int ks = 0; ks < 16; ++ks)
                    asm volatile("global_load_dwordx4 %0, %1, off sc0 sc1"
                                 : "=v"(Bf[ks].u) : "v"(hsrc + ks * 32) : "memory");
                asm volatile("s_waitcnt vmcnt(0)" ::: "memory");
                bool ok = true;
#pragma unroll
                for (int ks = 0; ks < 16; ++ks) {
                    ok = ok && (Bf[ks].u.x != SENTP) && (Bf[ks].u.y != SENTP) &&
                               (Bf[ks].u.z != SENTP) && (Bf[ks].u.w != SENTP);
                }
                if (__ballot(!ok) == 0ULL) break;
            }

            // ---- MFMA: A from LDS (ds_read_b128, conflict-free lane-linear) ----
#pragma unroll
            for (int ks = 0; ks < 16; ++ks) {
                short8 a0 = *(const short8*)(lA0 + ks * 512);
                short8 a1 = *(const short8*)(lA1 + ks * 512);
                acc0 = __builtin_amdgcn_mfma_f32_16x16x32_bf16(a0, Bf[ks].s, acc0, 0, 0, 0);
                acc1 = __builtin_amdgcn_mfma_f32_16x16x32_bf16(a1, Bf[ks].s, acc1, 0, 0, 0);
            }
        }

        // activations: lanes l<32 hold i (acc0) / g (acc1); f/o at lane+32
        float hreg[4];
#pragma unroll
        for (int r = 0; r < 4; ++r) {
            float gf = __shfl_down(acc0[r], 32, 64);
            float go = __shfl_down(acc1[r], 32, 64);
            float is = sigf(acc0[r]);
            float fs = sigf(gf);
            float gv = tanhf(acc1[r]);
            float os = sigf(go);
            c0[r] = fs * c0[r] + is * gv;
            hreg[r] = os * tanhf(c0[r]);
        }

        // all 4 waves of this block have consumed the (t-1) copy (their B loads are
        // complete -- drained inside the poll) before anyone resets it
        __syncthreads();

        if (t > 0) {
            // reset this wave's quarter of the consumed copy to sentinel (write-through)
            unsigned short* rb =
                hcp + (((size_t)((t - 1) & 1) * LBLK + bx) * (BB * HH)) + (size_t)wv * 1024;
            uint32x4 sv = {SENTP, SENTP, SENTP, SENTP};
            asm volatile("global_store_dwordx4 %0, %1, off sc0 sc1"
                         :: "v"(rb + (size_t)l * 16), "v"(sv) : "memory");
            asm volatile("global_store_dwordx4 %0, %1, off sc0 sc1"
                         :: "v"(rb + (size_t)l * 16 + 8), "v"(sv) : "memory");
        }

        if (l < 32 && b16 < BB) {
            const int ib = I0 + kg * 4;   // kg in {0,1}
            // f32 h for downstream kernels (plain cached; flushed at kernel end)
            *(float4*)(hall + ((size_t)t * BB + b16) * HH + ib) =
                make_float4(hreg[0], hreg[1], hreg[2], hreg[3]);
            if (t < NTOK - 1) {
                // publish bf16 h slice to all 16 per-block copies (write-through)
                u64 pk = (u64)f2bf(hreg[0]) | ((u64)f2bf(hreg[1]) << 16) |
                         ((u64)f2bf(hreg[2]) << 32) | ((u64)f2bf(hreg[3]) << 48);
#pragma unroll
                for (int q = 0; q < LBLK; ++q) {
                    unsigned short* dst =
                        hcp + (((size_t)(t & 1) * LBLK + q) * (BB * HH)) + (size_t)b16 * HH + ib;
                    asm volatile("global_store_dwordx2 %0, %1, off sc0 sc1"
                                 :: "v"(dst), "v"(pk) : "memory");
                }
            }
        }
        // single drain: orders reset + publish at the coherent point before the
        // next poll (and before this block's publish is observable to producers)
        asm volatile("s_waitcnt vmcnt(0)" ::: "memory");
    }
}

// ============ Kernel 3: Q = tanh(Hdec @ W_att^T). grid TM, block 256 ============
__global__ void __launch_bounds__(256) k_q(const float* __restrict__ hall,
                                           const float* __restrict__ Watt,
                                           float* __restrict__ q) {
    __shared__ float hb[8 * 516];
    const int t = blockIdx.x, tid = threadIdx.x;
    const float* hdec = hall + (size_t)(SS + t) * (BB * HH);
    for (int e = tid; e < BB * HH; e += 256)
        hb[(e >> 9) * 516 + (e & 511)] = hdec[e];
    __syncthreads();

    for (int oi = tid; oi < BB * HH; oi += 256) {
        int b = oi & 7, ii = oi >> 3;
        const float4* w4 = (const float4*)(Watt + (size_t)ii * HH);
        const float4* h4 = (const float4*)(hb + b * 516);
        float acc = 0.f;
        for (int k4 = 0; k4 < HH / 4; ++k4) {
            float4 w = w4[k4], h = h4[k4];
            acc += w.x * h.x + w.y * h.y + w.z * h.z + w.w * h.w;
        }
        q[(size_t)(t * BB + b) * HH + ii] = tanhf(acc);
    }
}

// ============ Kernel 4: attention scores + softmax + pointer gather ============
__global__ void __launch_bounds__(256) k_att(const float* __restrict__ hall,
                                             const float* __restrict__ q,
                                             const float* __restrict__ sent,
                                             const int* __restrict__ src,
                                             const int* __restrict__ tgt,
                                             float* __restrict__ pptr,
                                             float* __restrict__ asent) {
    __shared__ float qs[HH];
    __shared__ float av[256];
    __shared__ float red[256];
    const int t = blockIdx.x, b = blockIdx.y, tid = threadIdx.x;

    for (int e = tid; e < HH; e += 256) qs[e] = q[(size_t)(t * BB + b) * HH + e];
    __syncthreads();

    const int j = tid;
    float acc = NEGF;
    if (j < SS + TM + 1) {
        bool valid = (j < SS + t + 1) || (j == SS + TM);
        if (valid) {
            const float* vptr = (j < SS + TM) ? (hall + (size_t)(j * BB + b) * HH) : sent;
            const float4* v4 = (const float4*)vptr;
            const float4* q4 = (const float4*)qs;
            float a = 0.f;
            for (int k4 = 0; k4 < HH / 4; ++k4) {
                float4 v = v4[k4], qq = q4[k4];
                a += v.x * qq.x + v.y * qq.y + v.z * qq.z + v.w * qq.w;
            }
            acc = a;
        }
    }
    red[tid] = acc;
    __syncthreads();
    for (int s2 = 128; s2 > 0; s2 >>= 1) {
        if (tid < s2) red[tid] = fmaxf(red[tid], red[tid + s2]);
        __syncthreads();
    }
    float m = red[0];
    __syncthreads();
    float e = __expf(acc - m);
    red[tid] = e;
    __syncthreads();
    for (int s2 = 128; s2 > 0; s2 >>= 1) {
        if (tid < s2) red[tid] += red[tid + s2];
        __syncthreads();
    }
    float denom = red[0];
    __syncthreads();
    float a = e / denom;
    av[tid] = a;
    __syncthreads();

    const int vs = tgt[(t + 1) * BB + b];
    float contrib = 0.f;
    if (j < SS) {
        if (src[j * BB + b] == vs) contrib += av[j];        // a_src
        if (tgt[j * BB + b] == vs) contrib += av[SS + j];   // a_tgt
    }
    red[tid] = contrib;
    __syncthreads();
    for (int s2 = 128; s2 > 0; s2 >>= 1) {
        if (tid < s2) red[tid] += red[tid + s2];
        __syncthreads();
    }
    if (tid == 0) {
        pptr[t * BB + b]  = red[0];
        asent[t * BB + b] = av[SS + TM];
    }
}

// ============ Kernel 5: vocab softmax stats via bf16 MFMA ============
__global__ void __launch_bounds__(256) k_vocab_mfma(const unsigned short* __restrict__ Abf,
                                                    const unsigned short* __restrict__ Wbf,
                                                    const int* __restrict__ tgt,
                                                    float* __restrict__ ssum,
                                                    float* __restrict__ lstar) {
    const int tid  = threadIdx.x;
    const int wave = tid >> 6;
    const int lane = tid & 63;
    const int r16  = lane & 15;
    const int kg   = lane >> 4;          // 0..3
    const int n0   = blockIdx.x * 64;

    const unsigned short* b0 = Wbf + (size_t)(n0 +  0 + r16) * HH + kg * 8;
    const unsigned short* b1 = Wbf + (size_t)(n0 + 16 + r16) * HH + kg * 8;
    const unsigned short* b2 = Wbf + (size_t)(n0 + 32 + r16) * HH + kg * 8;
    const unsigned short* b3 = Wbf + (size_t)(n0 + 48 + r16) * HH + kg * 8;

    for (int pass = 0; pass < 12; ++pass) {
        const int row0 = pass * 64 + wave * 16;
        const unsigned short* arow = Abf + (size_t)(row0 + r16) * HH + kg * 8;

        f32x4 acc0 = {0.f,0.f,0.f,0.f}, acc1 = acc0, acc2 = acc0, acc3 = acc0;
#pragma unroll
        for (int ks = 0; ks < 16; ++ks) {
            short8 a = *(const short8*)(arow + ks * 32);
            acc0 = __builtin_amdgcn_mfma_f32_16x16x32_bf16(a, *(const short8*)(b0 + ks * 32), acc0, 0, 0, 0);
            acc1 = __builtin_amdgcn_mfma_f32_16x16x32_bf16(a, *(const short8*)(b1 + ks * 32), acc1, 0, 0, 0);
            acc2 = __builtin_amdgcn_mfma_f32_16x16x32_bf16(a, *(const short8*)(b2 + ks * 32), acc2, 0, 0, 0);
            acc3 = __builtin_amdgcn_mfma_f32_16x16x32_bf16(a, *(const short8*)(b3 + ks * 32), acc3, 0, 0, 0);
        }

#pragma unroll
        for (int reg = 0; reg < 4; ++reg) {
            const int rowg = row0 + 4 * kg + reg;
            const int vs = tgt[BB + rowg];
            int cg;
            cg = n0 +  0 + r16; if (cg == vs) lstar[rowg] = acc0[reg];
            cg = n0 + 16 + r16; if (cg == vs) lstar[rowg] = acc1[reg];
            cg = n0 + 32 + r16; if (cg == vs) lstar[rowg] = acc2[reg];
            cg = n0 + 48 + r16; if (cg == vs) lstar[rowg] = acc3[reg];

            float v = __expf(acc0[reg]) + __expf(acc1[reg]) +
                      __expf(acc2[reg]) + __expf(acc3[reg]);
            v += __shfl_xor(v, 1, 64);
            v += __shfl_xor(v, 2, 64);
            v += __shfl_xor(v, 4, 64);
            v += __shfl_xor(v, 8, 64);
            if (r16 == 0) atomicAdd(&ssum[rowg], v);
        }
    }
}

// ============ Kernel 5-fallback: f32 vocab stats (used if ws too small) ============
__global__ void __launch_bounds__(256) k_vocab_f32(const float* __restrict__ hall,
                                                   const float* __restrict__ Wread,
                                                   const int* __restrict__ tgt,
                                                   float* __restrict__ ssum,
                                                   float* __restrict__ lstar) {
    __shared__ float hs[32 * HH];   // 64 KB
    const int tid = threadIdx.x;
    const int v0 = blockIdx.x * 512 + tid * 2;
    const int v1 = v0 + 1;
    const bool g0 = v0 < VV, g1 = v1 < VV;
    const float4* w40 = (const float4*)(Wread + (size_t)(g0 ? v0 : 0) * HH);
    const float4* w41 = (const float4*)(Wread + (size_t)(g1 ? v1 : 0) * HH);
    const int rbase0 = blockIdx.y * 128;

    for (int ch = 0; ch < 4; ++ch) {
        const int rbase = rbase0 + ch * 32;
        const float4* sp4 = (const float4*)(hall + ((size_t)SS * BB + rbase) * HH);
        float4* hs4 = (float4*)hs;
        for (int e = tid; e < 32 * HH / 4; e += 256) hs4[e] = sp4[e];
        __syncthreads();

        float acc0[32], acc1[32];
#pragma unroll
        for (int r = 0; r < 32; ++r) { acc0[r] = 0.f; acc1[r] = 0.f; }

        for (int k4 = 0; k4 < HH / 4; ++k4) {
            float4 w0 = w40[k4];
            float4 w1 = w41[k4];
#pragma unroll
            for (int r = 0; r < 32; ++r) {
                float4 h = *((const float4*)(hs + r * HH + k4 * 4));
                acc0[r] += w0.x * h.x + w0.y * h.y + w0.z * h.z + w0.w * h.w;
                acc1[r] += w1.x * h.x + w1.y * h.y + w1.z * h.z + w1.w * h.w;
            }
        }

#pragma unroll
        for (int r = 0; r < 32; ++r) {
            const int row = rbase + r;
            float val = 0.f;
            if (g0) val += __expf(acc0[r]);
            if (g1) val += __expf(acc1[r]);
#pragma unroll
            for (int d = 32; d > 0; d >>= 1) val += __shfl_xor(val, d, 64);
            if ((tid & 63) == 0) atomicAdd(&ssum[row], val);
            const int vs = tgt[row + BB];
            if (g0 && v0 == vs) lstar[row] = acc0[r];
            else if (g1 && v1 == vs) lstar[row] = acc1[r];
        }
        __syncthreads();
    }
}

// ============ Kernel 6: gold log-likelihoods + per-batch sums ============
__global__ void __launch_bounds__(768) k_final(const float* __restrict__ pptr,
                                               const float* __restrict__ asent,
                                               const float* __restrict__ ssum,
                                               const float* __restrict__ lstar,
                                               const int* __restrict__ tgt,
                                               float* __restrict__ out) {
    __shared__ float g[TM * BB], gp[TM * BB];
    const int tid = threadIdx.x;          // = t*8+b
    const int vs = tgt[tid + BB];
    const float pv = __expf(lstar[tid]) / ssum[tid];
    const float ps = pptr[tid];
    const float as = asent[tid];
    if (vs != 0) {
        g[tid]  = logf(ps + pv * as);
        gp[tid] = logf(ps + as);
    } else {
        g[tid] = 0.f; gp[tid] = 0.f;
    }
    __syncthreads();
    if (tid < BB) {
        float s1 = 0.f, s2 = 0.f;
        for (int t = 0; t < TM; ++t) { s1 += g[t * BB + tid]; s2 += gp[t * BB + tid]; }
        out[tid] = s1;
        out[BB + tid] = s2;
    }
}

extern "C" void kernel_launch(void* const* d_in, const int* in_sizes, int n_in,
                              void* d_out, int out_size, void* d_ws, size_t ws_size,
                              hipStream_t stream) {
    (void)in_sizes; (void)n_in; (void)out_size;
    const int*   src   = (const int*)d_in[0];
    const int*   tgt   = (const int*)d_in[1];
    const float* emb   = (const float*)d_in[2];
    const float* Wih   = (const float*)d_in[3];
    const float* Whh   = (const float*)d_in[4];
    const float* bih   = (const float*)d_in[5];
    const float* bhh   = (const float*)d_in[6];
    const float* Watt  = (const float*)d_in[7];
    const float* sent  = (const float*)d_in[8];
    const float* Wread = (const float*)d_in[9];
    float* ws  = (float*)d_ws;
    float* out = (float*)d_out;

    const bool use_mfma_vocab = ws_size >= NEED_F * sizeof(float);

    // zero SSUM + LSTAR (contiguous)
    (void)hipMemsetAsync((void*)(ws + SSUM_OFF), 0,
                         (size_t)(TM * BB * 2) * sizeof(float), stream);

    k_xih<<<dim3(NTOK * BB / 16, G4 / 256), 256, 0, stream>>>(
        src, tgt, emb, Wih, bih, bhh, ws + XIH_OFF);

    // Whh -> bf16 (needed by k_lstm)
    k_cvt2<<<dim3((unsigned)((size_t)G4 * HH / 8 / 256)), 256, 0, stream>>>(
        Whh, (unsigned short*)(ws + WHHBF_OFF), (long)G4 * HH);

    // sentinel-init the h-copy region (every launch -> replay-deterministic)
    k_sent<<<dim3(64), 256, 0, stream>>>((unsigned*)(ws + HCP_OFF));

    {
        const float* xih = ws + XIH_OFF;
        const unsigned short* whhbf = (const unsigned short*)(ws + WHHBF_OFF);
        float* hall = ws + HALL_OFF;
        unsigned short* hcp = (unsigned short*)(ws + HCP_OFF);
        void* args[] = { (void*)&xih, (void*)&whhbf, (void*)&hall, (void*)&hcp };
        (void)hipLaunchCooperativeKernel((void*)k_lstm, dim3(LBLK), dim3(256), args,
                                         131072, stream);
    }

    k_q<<<dim3(TM), 256, 0, stream>>>(ws + HALL_OFF, Watt, ws + Q_OFF);

    k_att<<<dim3(TM, BB), 256, 0, stream>>>(ws + HALL_OFF, ws + Q_OFF, sent,
                                            src, tgt, ws + PPTR_OFF, ws + ASENT_OFF);

    if (use_mfma_vocab) {
        k_cvt2<<<dim3((unsigned)((size_t)VV * HH / 8 / 256)), 256, 0, stream>>>(
            Wread, (unsigned short*)(ws + WBF_OFF), (long)VV * HH);
        k_cvt2<<<dim3((unsigned)((size_t)768 * HH / 8 / 256)), 256, 0, stream>>>(
            ws + HALL_OFF + (size_t)SS * BB * HH, (unsigned short*)(ws + ABF_OFF),
            (long)768 * HH);
        k_vocab_mfma<<<dim3(VV / 64), 256, 0, stream>>>(
            (const unsigned short*)(ws + ABF_OFF),
            (const unsigned short*)(ws + WBF_OFF),
            tgt, ws + SSUM_OFF, ws + LSTAR_OFF);
    } else {
        k_vocab_f32<<<dim3(63, 6), 256, 0, stream>>>(ws + HALL_OFF, Wread, tgt,
                                                     ws + SSUM_OFF, ws + LSTAR_OFF);
    }

    k_final<<<dim3(1), dim3(TM * BB), 0, stream>>>(ws + PPTR_OFF, ws + ASENT_OFF,
                                                   ws + SSUM_OFF, ws + LSTAR_OFF,
                                                   tgt, out);
}